// Round 8
// baseline (281.828 us; speedup 1.0000x reference)
//
#include <hip/hip_runtime.h>

typedef unsigned short u16;
typedef unsigned int u32;
typedef short s8v __attribute__((ext_vector_type(8)));    // 8 bf16 (4 VGPRs)
typedef float f16v __attribute__((ext_vector_type(16)));  // 32x32 mfma acc

#define NHW 4096    // H*W
#define CIN 256     // C
#define CID 128     // CI (inter channels)
#define PB  524288  // per-batch frag elems for Q/K/V/O (NHW*CID)
#define XSZ 1048576 // per-(input,batch) Xf elems (NHW*CIN)

__device__ __forceinline__ u16 f2bf(float f) {
  union { float f; u32 u; } v; v.f = f;
  u32 r = v.u + 0x7fffu + ((v.u >> 16) & 1u);
  return (u16)(r >> 16);
}
__device__ __forceinline__ u32 pk2(float a, float b) {
  return (u32)f2bf(a) | ((u32)f2bf(b) << 16);
}
__device__ __forceinline__ int SIG(int reg, int h) {
  return (reg & 3) + 8 * (reg >> 2) + 4 * h;
}

// Layouts (all verified by the passing R7 kernel, unchanged):
//  Qf/Kf[nblk128][ct4][hp2][lm32][r16], Vf[mblk128][ct4][ks2][hp2][lm32][j8],
//  Of[nblk128][ks8][h2][lm32][j8], Wf[p3][ct4][ksg16][h2][lm32][j8],
//  Wf2[ct8][ks8][h2][lm32][j8].
// New: Xf[(p,b)][nblk128][ksg16][h2][lm32][j8] : X[n=nblk*32+lm][c=ksg*16+h*8+j] bf16.

// ---------------------------------------------------------------------------
// Kernel 0: weight prep (unchanged from R7).
// ---------------------------------------------------------------------------
__global__ __launch_bounds__(256) void wprep_kernel(
    const float* __restrict__ tw, const float* __restrict__ pw, const float* __restrict__ gw,
    const float* __restrict__ ww, const float* __restrict__ wb,
    const float* __restrict__ bg, const float* __restrict__ bb,
    const float* __restrict__ bm, const float* __restrict__ bv,
    u16* __restrict__ Wf, u16* __restrict__ Wf2,
    float* __restrict__ scl, float* __restrict__ offs)
{
  const int bid = blockIdx.x, t = threadIdx.x;
  const int lm = t & 31, h = (t >> 5) & 1, g4 = t >> 6;
  if (bid < 12) {
    const int p = bid >> 2, ct = bid & 3;
    const float* W = (p == 0) ? tw : (p == 1) ? pw : gw;
#pragma unroll
    for (int q = 0; q < 4; ++q) {
      const int ksg = g4 * 4 + q;
      const float* src = W + (size_t)(ct * 32 + lm) * 256 + ksg * 16 + h * 8;
      u32 pk[4];
#pragma unroll
      for (int e = 0; e < 4; ++e) pk[e] = pk2(src[2 * e], src[2 * e + 1]);
      *(uint4*)(Wf + p * 32768 + ct * 8192 + ksg * 512 + h * 256 + lm * 8) =
          make_uint4(pk[0], pk[1], pk[2], pk[3]);
    }
  } else if (bid < 20) {
    const int ct = bid - 12;
#pragma unroll
    for (int q = 0; q < 2; ++q) {
      const int ks = g4 * 2 + q;
      const float* src = ww + (size_t)(ct * 32 + lm) * 128 + ks * 16 + h * 8;
      u32 pk[4];
#pragma unroll
      for (int e = 0; e < 4; ++e) pk[e] = pk2(src[2 * e], src[2 * e + 1]);
      *(uint4*)(Wf2 + ct * 8192 + ks * 512 + h * 256 + lm * 8) =
          make_uint4(pk[0], pk[1], pk[2], pk[3]);
    }
  } else {
    float inv = bg[t] * __frsqrt_rn(bv[t] + 1e-5f);
    scl[t] = inv;
    offs[t] = (wb[t] - bm[t]) * inv + bb[t];
  }
}

// ---------------------------------------------------------------------------
// Kernel 0b: X transpose/convert to frag-major bf16.
// grid (NHW/64, B, 3), block 256.  Two c-passes of 128 rows (LDS 34.8 KB).
// Loads: 16-row x 256B segments (fully line-covered).  Stores: 1KB/wave contig.
// ---------------------------------------------------------------------------
__global__ __launch_bounds__(256) void xprep_kernel(
    const float* __restrict__ x, const float* __restrict__ y, const float* __restrict__ zz,
    u16* __restrict__ X0, u16* __restrict__ X1, u16* __restrict__ X2)
{
  __shared__ __align__(16) float Xs[128][68];
  const int t = threadIdx.x;
  const int b = blockIdx.y, p = blockIdx.z;
  const int n0 = blockIdx.x * 64;
  const float* in = (p == 0) ? x : (p == 1) ? y : zz;
  u16* Xf = ((p == 0) ? X0 : (p == 1) ? X1 : X2) + (size_t)b * XSZ +
            (size_t)blockIdx.x * 2 * 8192;
  const int lm = t & 31, h = (t >> 5) & 1, nb = (t >> 6) & 1, q = t >> 7;
  const int cr = t >> 4, ns = t & 15;

  for (int pass = 0; pass < 2; ++pass) {
    if (pass) __syncthreads();  // pass-0 packs done before Xs overwrite
#pragma unroll
    for (int is = 0; is < 8; ++is) {
      int c = pass * 128 + is * 16 + cr;
      *(float4*)&Xs[is * 16 + cr][ns * 4] =
          *(const float4*)(in + (size_t)(b * CIN + c) * NHW + n0 + ns * 4);
    }
    __syncthreads();
#pragma unroll
    for (int i = 0; i < 4; ++i) {
      const int ksgl = q * 4 + i;
      const int c0 = ksgl * 16 + h * 8;
      float v[8];
#pragma unroll
      for (int j = 0; j < 8; ++j) v[j] = Xs[c0 + j][nb * 32 + lm];
      uint4 pk = make_uint4(pk2(v[0], v[1]), pk2(v[2], v[3]),
                            pk2(v[4], v[5]), pk2(v[6], v[7]));
      *(uint4*)(Xf + nb * 8192 + (pass * 8 + ksgl) * 512 + h * 256 + lm * 8) = pk;
    }
  }
}

// ---------------------------------------------------------------------------
// Kernel 1: pure-frag MFMA projections (no LDS staging).
// grid (NHW/64, B, 3) = 768 blocks, block 256 (4 waves).
// Wave: nt = wave&1 (n-tile of 32), cih = wave>>1 (ci-half, 2 ct).
// p<2: D = W·X -> Qf/Kf;  p=2: D = X·W -> Vf (same frag bits, swapped operands).
// ---------------------------------------------------------------------------
__global__ __launch_bounds__(256) void proj_kernel(
    const u16* __restrict__ X0, const u16* __restrict__ X1, const u16* __restrict__ X2,
    const u16* __restrict__ Wf,
    const float* __restrict__ tb, const float* __restrict__ pb, const float* __restrict__ gb,
    u16* __restrict__ Qf, u16* __restrict__ Kf, u16* __restrict__ Vf)
{
  __shared__ float Bs[128];
  const int t = threadIdx.x;
  const int b = blockIdx.y, p = blockIdx.z;
  const float* Bv = (p == 0) ? tb : (p == 1) ? pb : gb;
  u16* out = (p == 0) ? Qf : (p == 1) ? Kf : Vf;
  const int wave = t >> 6, lane = t & 63, lm = lane & 31, h = lane >> 5;
  const int nt = wave & 1, cih = wave >> 1;
  if (t < 128) Bs[t] = Bv[t];
  __syncthreads();

  const u16* Xb = ((p == 0) ? X0 : (p == 1) ? X1 : X2) + (size_t)b * XSZ +
                  ((size_t)blockIdx.x * 2 + nt) * 8192 + lane * 8;
  const u16* Wb = Wf + p * 32768 + cih * 2 * 8192 + lane * 8;

  f16v a0, a1;
#pragma unroll
  for (int r = 0; r < 16; ++r) { a0[r] = 0.f; a1[r] = 0.f; }

  if (p < 2) {
#pragma unroll 4
    for (int ksg = 0; ksg < 16; ++ksg) {
      s8v xf = *(const s8v*)(Xb + ksg * 512);
      s8v w0 = *(const s8v*)(Wb + ksg * 512);
      s8v w1 = *(const s8v*)(Wb + 8192 + ksg * 512);
      a0 = __builtin_amdgcn_mfma_f32_32x32x16_bf16(w0, xf, a0, 0, 0, 0);
      a1 = __builtin_amdgcn_mfma_f32_32x32x16_bf16(w1, xf, a1, 0, 0, 0);
    }
  } else {
#pragma unroll 4
    for (int ksg = 0; ksg < 16; ++ksg) {
      s8v xf = *(const s8v*)(Xb + ksg * 512);
      s8v w0 = *(const s8v*)(Wb + ksg * 512);
      s8v w1 = *(const s8v*)(Wb + 8192 + ksg * 512);
      a0 = __builtin_amdgcn_mfma_f32_32x32x16_bf16(xf, w0, a0, 0, 0, 0);
      a1 = __builtin_amdgcn_mfma_f32_32x32x16_bf16(xf, w1, a1, 0, 0, 0);
    }
  }

  const size_t nblk = (size_t)blockIdx.x * 2 + nt;
  if (p < 2) {
#pragma unroll
    for (int cti = 0; cti < 2; ++cti) {
      const int ct = cih * 2 + cti;
      const f16v& ac = cti ? a1 : a0;
      float v[16];
#pragma unroll
      for (int reg = 0; reg < 16; ++reg) v[reg] = ac[reg] + Bs[ct * 32 + SIG(reg, h)];
      u32 pk[8];
#pragma unroll
      for (int e = 0; e < 8; ++e) pk[e] = pk2(v[2 * e], v[2 * e + 1]);
      u16* dst = out + (size_t)b * PB + nblk * 4096 + ct * 1024 + h * 512 + lm * 16;
      ((uint4*)dst)[0] = make_uint4(pk[0], pk[1], pk[2], pk[3]);
      ((uint4*)dst)[1] = make_uint4(pk[4], pk[5], pk[6], pk[7]);
    }
  } else {
#pragma unroll
    for (int cti = 0; cti < 2; ++cti) {
      const int ct = cih * 2 + cti;
      const f16v& ac = cti ? a1 : a0;
      const float bias = Bs[ct * 32 + lm];
      u32 pk[8];
#pragma unroll
      for (int e = 0; e < 8; ++e) pk[e] = pk2(ac[2 * e] + bias, ac[2 * e + 1] + bias);
      u16* dst = out + (size_t)b * PB + nblk * 4096 + ct * 1024 + h * 256 + lm * 8;
      *(uint4*)dst         = make_uint4(pk[0], pk[1], pk[2], pk[3]);
      *(uint4*)(dst + 512) = make_uint4(pk[4], pk[5], pk[6], pk[7]);
    }
  }
}

// ---------------------------------------------------------------------------
// Kernel 2: MFMA flash attention v6 — 8 waves/block for 2x occupancy.
// grid (NHW/32, B), block 512.  Wave w: m-eighth [w*512,+512), 16 iters.
// ---------------------------------------------------------------------------
__global__ __launch_bounds__(512, 4) void attn_kernel(
    const u16* __restrict__ Qf, const u16* __restrict__ Kf,
    const u16* __restrict__ Vf, u16* __restrict__ Of)
{
  __shared__ __align__(16) float Obuf[32][132];
  __shared__ float lbuf[32];
  const int t = threadIdx.x;
  const int wave = t >> 6, lane = t & 63;
  const int lm = lane & 31, half = lane >> 5;
  const int b = blockIdx.y;

  s8v qf[8];
  {
    const u16* qp = Qf + (size_t)b * PB + (size_t)blockIdx.x * 4096 + lm * 16 + half * 8;
#pragma unroll
    for (int ks = 0; ks < 8; ++ks) qf[ks] = *(const s8v*)(qp + ks * 512);
  }

  const u16* Kb = Kf + (size_t)b * PB + lm * 16 + half * 8;
  const u16* Vb = Vf + (size_t)b * PB + half * 256 + lm * 8;
  const int mstart = wave * 512;

  f16v oacc[4];
#pragma unroll
  for (int c = 0; c < 4; ++c)
#pragma unroll
    for (int r = 0; r < 16; ++r) oacc[c][r] = 0.f;
  float lacc = 0.f;

  s8v kf[8];
  {
    const u16* kp = Kb + (size_t)mstart * 128;
#pragma unroll
    for (int ks = 0; ks < 8; ++ks) kf[ks] = *(const s8v*)(kp + ks * 512);
  }

  for (int jt = 0; jt < 16; ++jt) {
    const int m0 = mstart + jt * 32;

    s8v vf[8];
    {
      const u16* vp = Vb + (size_t)m0 * 128;
#pragma unroll
      for (int ct = 0; ct < 4; ++ct)
#pragma unroll
        for (int ks = 0; ks < 2; ++ks)
          vf[ct * 2 + ks] = *(const s8v*)(vp + ct * 1024 + ks * 512);
    }

    f16v sacc;
#pragma unroll
    for (int r = 0; r < 16; ++r) sacc[r] = 0.f;
#pragma unroll
    for (int ks = 0; ks < 8; ++ks)
      sacc = __builtin_amdgcn_mfma_f32_32x32x16_bf16(kf[ks], qf[ks], sacc, 0, 0, 0);

    {
      const u16* kp = Kb + (size_t)(m0 + 32) * 128;
#pragma unroll
      for (int ks = 0; ks < 8; ++ks) kf[ks] = *(const s8v*)(kp + ks * 512);
    }

    union { s8v v; u16 e[8]; } pa0, pa1;
#pragma unroll
    for (int j = 0; j < 8; ++j) {
      float p0 = __expf(sacc[j]);
      float p1 = __expf(sacc[8 + j]);
      lacc += p0 + p1;
      pa0.e[j] = f2bf(p0);
      pa1.e[j] = f2bf(p1);
    }

#pragma unroll
    for (int ct = 0; ct < 4; ++ct) {
      oacc[ct] = __builtin_amdgcn_mfma_f32_32x32x16_bf16(pa0.v, vf[ct * 2 + 0], oacc[ct], 0, 0, 0);
      oacc[ct] = __builtin_amdgcn_mfma_f32_32x32x16_bf16(pa1.v, vf[ct * 2 + 1], oacc[ct], 0, 0, 0);
    }
  }

  lacc += __shfl_xor(lacc, 32);

  __syncthreads();
  if (wave == 0) {
#pragma unroll
    for (int ct = 0; ct < 4; ++ct)
#pragma unroll
      for (int reg = 0; reg < 16; ++reg)
        Obuf[SIG(reg, half)][ct * 32 + lm] = oacc[ct][reg];
    if (half == 0) lbuf[lm] = lacc;
  }
  __syncthreads();
  if (wave != 0) {
#pragma unroll
    for (int ct = 0; ct < 4; ++ct)
#pragma unroll
      for (int reg = 0; reg < 16; ++reg)
        atomicAdd(&Obuf[SIG(reg, half)][ct * 32 + lm], oacc[ct][reg]);
    if (half == 0) atomicAdd(&lbuf[lm], lacc);
  }
  __syncthreads();

  // normalize + store Of frag-major; wave w stores ks = w
  {
    const float inv = 1.0f / lbuf[lm];
    u16* ob = Of + (size_t)b * PB + (size_t)blockIdx.x * 4096 + half * 256 + lm * 8;
    float4 va = *(const float4*)&Obuf[lm][wave * 16 + half * 8];
    float4 vb = *(const float4*)&Obuf[lm][wave * 16 + half * 8 + 4];
    uint4 pk = make_uint4(pk2(va.x * inv, va.y * inv), pk2(va.z * inv, va.w * inv),
                          pk2(vb.x * inv, vb.y * inv), pk2(vb.z * inv, vb.w * inv));
    *(uint4*)(ob + wave * 512) = pk;
  }
}

// ---------------------------------------------------------------------------
// Kernel 3: MFMA out-projection + BN + residual (unchanged from R7).
// ---------------------------------------------------------------------------
__global__ __launch_bounds__(256) void outproj_kernel(
    const u16* __restrict__ Of, const float* __restrict__ zz,
    const u16* __restrict__ Wf2, const float* __restrict__ scl,
    const float* __restrict__ offs, float* __restrict__ out)
{
  __shared__ float SC[256], OFS[256];
  const int t = threadIdx.x;
  const int wave = t >> 6, lane = t & 63;
  const int lm = lane & 31, h = lane >> 5;
  const int b = blockIdx.y;
  const int n0 = blockIdx.x * 32;

  SC[t] = scl[t];
  OFS[t] = offs[t];
  __syncthreads();

  s8v of[8];
  {
    const u16* op = Of + (size_t)b * PB + (size_t)blockIdx.x * 4096 + h * 256 + lm * 8;
#pragma unroll
    for (int ks = 0; ks < 8; ++ks) of[ks] = *(const s8v*)(op + ks * 512);
  }

  f16v a0, a1;
#pragma unroll
  for (int r = 0; r < 16; ++r) { a0[r] = 0.f; a1[r] = 0.f; }

  const u16* w2a = Wf2 + (wave * 2 + 0) * 8192 + h * 256 + lm * 8;
  const u16* w2b = Wf2 + (wave * 2 + 1) * 8192 + h * 256 + lm * 8;
#pragma unroll
  for (int ks = 0; ks < 8; ++ks) {
    s8v wa = *(const s8v*)(w2a + ks * 512);
    s8v wb = *(const s8v*)(w2b + ks * 512);
    a0 = __builtin_amdgcn_mfma_f32_32x32x16_bf16(wa, of[ks], a0, 0, 0, 0);
    a1 = __builtin_amdgcn_mfma_f32_32x32x16_bf16(wb, of[ks], a1, 0, 0, 0);
  }

#pragma unroll
  for (int cti = 0; cti < 2; ++cti) {
    const int ct = wave * 2 + cti;
    const f16v& ac = cti ? a1 : a0;
#pragma unroll
    for (int reg = 0; reg < 16; ++reg) {
      const int co = ct * 32 + SIG(reg, h);
      const size_t idx = ((size_t)(b * CIN + co)) * NHW + n0 + lm;
      out[idx] = ac[reg] * SC[co] + OFS[co] + zz[idx];
    }
  }
}

// ---------------------------------------------------------------------------
extern "C" void kernel_launch(void* const* d_in, const int* in_sizes, int n_in,
                              void* d_out, int out_size, void* d_ws, size_t ws_size,
                              hipStream_t stream) {
  const float* x  = (const float*)d_in[0];
  const float* y  = (const float*)d_in[1];
  const float* z  = (const float*)d_in[2];
  const float* tw = (const float*)d_in[3];
  const float* tb = (const float*)d_in[4];
  const float* pw = (const float*)d_in[5];
  const float* pb = (const float*)d_in[6];
  const float* gw = (const float*)d_in[7];
  const float* gb = (const float*)d_in[8];
  const float* ww = (const float*)d_in[9];
  const float* wb = (const float*)d_in[10];
  const float* bn_g = (const float*)d_in[11];
  const float* bn_b = (const float*)d_in[12];
  const float* bn_m = (const float*)d_in[13];
  const float* bn_v = (const float*)d_in[14];

  const size_t B = 4;
  char* ws = (char*)d_ws;
  u16* Qf  = (u16*)ws;
  u16* Kf  = Qf + 4 * (size_t)PB;
  u16* Vf  = Kf + 4 * (size_t)PB;
  u16* XfA = Vf + 4 * (size_t)PB;              // p0 X-frags (8 MB)
  u16* XfB = XfA + 4 * (size_t)XSZ;            // p1 X-frags (8 MB)
  u16* Wf  = XfB + 4 * (size_t)XSZ;
  u16* Wf2 = Wf + 3 * 32768;
  float* scl  = (float*)(Wf2 + 65536);
  float* offs = scl + 256;
  u16* XfC = (u16*)d_out;   // p2 X-frags: d_out as scratch (overwritten by outproj)
  u16* Of  = XfA;           // alias: proj consumes XfA before attn writes Of

  float* out = (float*)d_out;

  wprep_kernel<<<21, 256, 0, stream>>>(tw, pw, gw, ww, wb, bn_g, bn_b, bn_m, bn_v,
                                       Wf, Wf2, scl, offs);
  xprep_kernel<<<dim3(NHW / 64, B, 3), 256, 0, stream>>>(x, y, z, XfA, XfB, XfC);
  proj_kernel<<<dim3(NHW / 64, B, 3), 256, 0, stream>>>(
      XfA, XfB, XfC, Wf, tb, pb, gb, Qf, Kf, Vf);
  attn_kernel<<<dim3(NHW / 32, B), 512, 0, stream>>>(Qf, Kf, Vf, Of);
  outproj_kernel<<<dim3(NHW / 32, B), 256, 0, stream>>>(
      Of, z, Wf2, scl, offs, out);
}